// Round 6
// baseline (473.652 us; speedup 1.0000x reference)
//
#include <hip/hip_runtime.h>
#include <hip/hip_bf16.h>
#include <stdint.h>
#include <math.h>

// ---------------------------------------------------------------------------
// Attention_74852690035363 — f32 I/O, bf16 MFMA compute.
//   M     = svd_tok·svd_tokᵀ            [nt64, 512 blk]
//   x2    = hs·M (M symmetric)          [nt64, 512 blk]
//   prep  = Wrot (48 batches) + tsrT (16 batches) in ONE launch [1024 blk]
//   mixed = x2·Wrotᵀ + brot             [nt64, 1536 blk; v-tiles also written
//                                        transposed into vT in the epilogue]
//   flash = fused exp(scale·q·kᵀ) causal / rowsum / P·V -> ctx
//   out   = ctx·tsrTᵀ + dense_b         [nt64, f32 store]
// LDS tiles 16B-chunk XOR-swizzled (round-4 verified: SQ_LDS_BANK_CONFLICT=0).
// ---------------------------------------------------------------------------

typedef __bf16 bf16_t;
typedef __bf16 bf16x8 __attribute__((ext_vector_type(8)));
typedef __bf16 bf16x4 __attribute__((ext_vector_type(4)));
typedef float  f32x4  __attribute__((ext_vector_type(4)));

__device__ __forceinline__ void async16(const void* g, void* l) {
  __builtin_amdgcn_global_load_lds(
      (const __attribute__((address_space(1))) void*)(uintptr_t)g,
      (__attribute__((address_space(3))) void*)(uint32_t)(uintptr_t)l,
      16, 0, 0);
}

// ---------------- 64x128-tile NT GEMM (BK=32) ------------------------------
// C[m,n] = alpha*sum_k A[m,k]*B[n,k] (+bias)
// flags&4:  f32 C + f32 bias
// flags&8:  bf16 bias
// flags&16: v-mirror: col-tiles with bx%3==2 (the rotated-V head blocks of
//           `mixed`) are also stored transposed into vmir[h][e][row]
__global__ __launch_bounds__(256)
void gemm_nt64(const bf16_t* __restrict__ A, const bf16_t* __restrict__ B,
               void* __restrict__ Cv, const void* __restrict__ biasv,
               int K, int lda, int ldb, int ldc, float alpha, int flags,
               bf16_t* __restrict__ vmir)
{
  const int bm0 = blockIdx.y * 64;
  const int bn0 = blockIdx.x * 128;

  __shared__ bf16_t shA[64 * 32];
  __shared__ bf16_t shB[128 * 32];

  const int t  = threadIdx.x;
  const int w  = t >> 6;
  const int l  = t & 63;
  const int wm = (w >> 1) * 32;            // 2x2 waves, wave tile 32x64
  const int wn = (w & 1) * 64;
  const int r0 = l >> 2;
  const int c0 = ((l & 3) ^ ((l >> 3) & 3)) * 8;
  const int fr = l & 15;
  const int kc = l >> 4;
  const int swr = ((fr >> 1) & 3);

  f32x4 acc[2][4];
  #pragma unroll
  for (int i = 0; i < 2; ++i)
    #pragma unroll
    for (int j = 0; j < 4; ++j)
      #pragma unroll
      for (int r = 0; r < 4; ++r)
        acc[i][j][r] = 0.0f;

  for (int k0 = 0; k0 < K; k0 += 32) {
    #pragma unroll
    for (int c = 0; c < 3; ++c) {
      const int seg = c * 4 + w;           // 0..3 -> A, 4..11 -> B
      if (seg < 4)
        async16(A + (long long)(bm0 + seg * 16 + r0) * lda + (k0 + c0), &shA[seg * 512]);
      else
        async16(B + (long long)(bn0 + (seg - 4) * 16 + r0) * ldb + (k0 + c0), &shB[(seg - 4) * 512]);
    }
    __builtin_amdgcn_s_waitcnt(0);
    __syncthreads();

    const int rc = (kc ^ swr) * 8;
    bf16x8 af[2], bfv[4];
    #pragma unroll
    for (int i = 0; i < 2; ++i)
      af[i]  = *(const bf16x8*)&shA[(wm + i * 16 + fr) * 32 + rc];
    #pragma unroll
    for (int j = 0; j < 4; ++j)
      bfv[j] = *(const bf16x8*)&shB[(wn + j * 16 + fr) * 32 + rc];
    #pragma unroll
    for (int i = 0; i < 2; ++i)
      #pragma unroll
      for (int j = 0; j < 4; ++j)
        acc[i][j] = __builtin_amdgcn_mfma_f32_16x16x32_bf16(af[i], bfv[j], acc[i][j], 0, 0, 0);
    __syncthreads();
  }

  const int cc = l & 15;
  const int rq = (l >> 4) * 4;
  if (flags & 4) {
    float* C = (float*)Cv;
    const float* bias = (const float*)biasv;
    #pragma unroll
    for (int j = 0; j < 4; ++j) {
      const int col = bn0 + wn + j * 16 + cc;
      const float bv = bias ? bias[col] : 0.0f;
      #pragma unroll
      for (int i = 0; i < 2; ++i)
        #pragma unroll
        for (int r = 0; r < 4; ++r) {
          const int row = bm0 + wm + i * 16 + rq + r;
          C[(long long)row * ldc + col] = acc[i][j][r] * alpha + bv;
        }
    }
  } else {
    bf16_t* C = (bf16_t*)Cv;
    const bf16_t* bias = (flags & 8) ? (const bf16_t*)biasv : nullptr;
    const bool mir = (flags & 16) && ((blockIdx.x % 3) == 2);
    const int h = bn0 / 384;
    bf16_t* vp = mir ? (vmir + (long long)h * 262144) : nullptr;
    const int e0 = bn0 - (h * 384 + 256);      // 0 for whole-tile v-blocks
    #pragma unroll
    for (int j = 0; j < 4; ++j) {
      const int col = bn0 + wn + j * 16 + cc;
      const float bv = bias ? (float)bias[col] : 0.0f;
      const int e = e0 + wn + j * 16 + cc;
      #pragma unroll
      for (int i = 0; i < 2; ++i)
        #pragma unroll
        for (int r = 0; r < 4; ++r) {
          const int row = bm0 + wm + i * 16 + rq + r;
          const bf16_t v = (bf16_t)(acc[i][j][r] * alpha + bv);
          C[(long long)row * ldc + col] = v;
          if (mir) vp[(long long)e * 2048 + row] = v;
        }
    }
  }
}

// ---------------- merged prep GEMMs: Wrot (z<48) + tsrT (z>=48) ------------
// 128x128 tile, K=128 (4 iters), lda=ldb=128, ldc=2048.
// z<48 (z=3h+p):  Wrot[z*128 + m][n] = sum_d Rot[h][d][m]*qkv_wT[z][n][d]
//                 (Rot = vlT for p==2 else qkT; A=RotT so rows are m=e)
// z>=48 (b=z-48): tsrT[o][b*128+e] = sum_d dwT[b][o][d]*vlT[b][e][d]
__global__ __launch_bounds__(256)
void gemm_prep(const bf16_t* __restrict__ qkT, const bf16_t* __restrict__ vlT,
               const bf16_t* __restrict__ qkv_wT, const bf16_t* __restrict__ dwT,
               bf16_t* __restrict__ Wrot, bf16_t* __restrict__ tsrT)
{
  const int z = blockIdx.z;
  const bf16_t* A;
  const bf16_t* B;
  bf16_t* C;
  int bm0, bn0;
  if (z < 48) {
    const int h = z / 3, p = z - 3 * h;
    A = (p == 2 ? vlT : qkT) + h * 16384;
    B = qkv_wT + (long long)z * 262144;
    C = Wrot + (long long)z * 262144;
    bm0 = 0;
    bn0 = blockIdx.x * 128;
  } else {
    const int b = z - 48;
    A = dwT + (long long)b * 262144;
    B = vlT + b * 16384;
    C = tsrT;
    bm0 = blockIdx.x * 128;
    bn0 = b * 128;
  }

  __shared__ bf16_t shA[128 * 32];
  __shared__ bf16_t shB[128 * 32];

  const int t  = threadIdx.x;
  const int w  = t >> 6;
  const int l  = t & 63;
  const int wm = (w >> 1) * 64;
  const int wn = (w & 1) * 64;
  const int r0 = l >> 2;
  const int c0 = ((l & 3) ^ ((l >> 3) & 3)) * 8;
  const int fr = l & 15;
  const int kc = l >> 4;
  const int swr = ((fr >> 1) & 3);

  f32x4 acc[4][4];
  #pragma unroll
  for (int i = 0; i < 4; ++i)
    #pragma unroll
    for (int j = 0; j < 4; ++j)
      #pragma unroll
      for (int r = 0; r < 4; ++r)
        acc[i][j][r] = 0.0f;

  for (int k0 = 0; k0 < 128; k0 += 32) {
    #pragma unroll
    for (int c = 0; c < 2; ++c) {
      const int seg = w * 2 + c;
      const int row = seg * 16 + r0;
      async16(A + (long long)((z < 48 ? 0 : bm0) + row) * 128 + (k0 + c0), &shA[seg * 512]);
      async16(B + (long long)((z < 48 ? bn0 : 0) + row) * 128 + (k0 + c0), &shB[seg * 512]);
    }
    __builtin_amdgcn_s_waitcnt(0);
    __syncthreads();

    const int rc = (kc ^ swr) * 8;
    bf16x8 af[4], bfv[4];
    #pragma unroll
    for (int i = 0; i < 4; ++i) {
      af[i]  = *(const bf16x8*)&shA[(wm + i * 16 + fr) * 32 + rc];
      bfv[i] = *(const bf16x8*)&shB[(wn + i * 16 + fr) * 32 + rc];
    }
    #pragma unroll
    for (int i = 0; i < 4; ++i)
      #pragma unroll
      for (int j = 0; j < 4; ++j)
        acc[i][j] = __builtin_amdgcn_mfma_f32_16x16x32_bf16(af[i], bfv[j], acc[i][j], 0, 0, 0);
    __syncthreads();
  }

  const int cc = l & 15;
  const int rq = (l >> 4) * 4;
  #pragma unroll
  for (int j = 0; j < 4; ++j) {
    const int col = bn0 + wn + j * 16 + cc;
    #pragma unroll
    for (int i = 0; i < 4; ++i)
      #pragma unroll
      for (int r = 0; r < 4; ++r) {
        const int row = (z < 48 ? 0 : bm0) + wm + i * 16 + rq + r;
        const int ccol = (z < 48 ? col : bn0 + wn + j * 16 + cc);
        C[(long long)row * 2048 + ccol] = (bf16_t)acc[i][j][r];
      }
  }
}

// ---------------------------------------------------------------------------
// Flash attention (verified rounds 4-5): one block = 64 q-rows x one head.
// ---------------------------------------------------------------------------
__global__ __launch_bounds__(256)
void flash_k(const bf16_t* __restrict__ mixed, const bf16_t* __restrict__ vT,
             bf16_t* __restrict__ ctx, float iscale)
{
  const int h  = blockIdx.y;
  const int qt = 31 - (int)blockIdx.x;
  const int r0g = qt * 64;
  const int niter = (qt >> 1) + 1;
  const bf16_t* Qp = mixed + h * 384;
  const bf16_t* Kp = mixed + h * 384 + 128;
  const bf16_t* Vp = vT + (long long)h * 262144;

  __shared__ bf16_t sKV[128 * 128];
  __shared__ bf16_t sP[64 * 136];
  __shared__ float  sL[2][64];

  const int t  = threadIdx.x;
  const int w  = t >> 6;
  const int l  = t & 63;
  const int wm = (w >> 1) * 32;
  const int wn = (w & 1) * 64;
  const int fr = l & 15;
  const int kc = l >> 4;

  bf16x8 aq[2][4];
  #pragma unroll
  for (int i = 0; i < 2; ++i)
    #pragma unroll
    for (int ks = 0; ks < 4; ++ks)
      aq[i][ks] = *(const bf16x8*)(Qp + (long long)(r0g + wm + i * 16 + fr) * 6144
                                      + ks * 32 + kc * 8);

  f32x4 oacc[2][4];
  #pragma unroll
  for (int i = 0; i < 2; ++i)
    #pragma unroll
    for (int j = 0; j < 4; ++j)
      #pragma unroll
      for (int r = 0; r < 4; ++r) oacc[i][j][r] = 0.0f;
  float lsum[2][4];
  #pragma unroll
  for (int i = 0; i < 2; ++i)
    #pragma unroll
    for (int r = 0; r < 4; ++r) lsum[i][r] = 0.0f;

  for (int it = 0; it < niter; ++it) {
    const int t0 = it * 128;
    #pragma unroll
    for (int s = 0; s < 8; ++s) {
      const int chunk = (w * 8 + s) * 64 + l;
      const int r = chunk >> 4;
      const int c = (chunk & 15) ^ (r & 7);
      async16(Kp + (long long)(t0 + r) * 6144 + c * 8, &sKV[(w * 8 + s) * 512]);
    }
    __builtin_amdgcn_s_waitcnt(0);
    __syncthreads();

    f32x4 acc[2][4];
    #pragma unroll
    for (int i = 0; i < 2; ++i)
      #pragma unroll
      for (int j = 0; j < 4; ++j)
        #pragma unroll
        for (int r = 0; r < 4; ++r) acc[i][j][r] = 0.0f;
    #pragma unroll
    for (int ks = 0; ks < 4; ++ks) {
      bf16x8 bk[4];
      #pragma unroll
      for (int j = 0; j < 4; ++j) {
        const int r = wn + j * 16 + fr;
        const int c = (ks * 4 + kc) ^ (r & 7);
        bk[j] = *(const bf16x8*)&sKV[r * 128 + c * 8];
      }
      #pragma unroll
      for (int i = 0; i < 2; ++i)
        #pragma unroll
        for (int j = 0; j < 4; ++j)
          acc[i][j] = __builtin_amdgcn_mfma_f32_16x16x32_bf16(aq[i][ks], bk[j], acc[i][j], 0, 0, 0);
    }

    #pragma unroll
    for (int i = 0; i < 2; ++i) {
      #pragma unroll
      for (int r = 0; r < 4; ++r) {
        const int rowl = wm + i * 16 + kc * 4 + r;
        const int Rg = r0g + rowl;
        float rs = 0.f;
        #pragma unroll
        for (int j = 0; j < 4; ++j) {
          const int coll = wn + j * 16 + fr;
          const float e = (t0 + coll <= Rg) ? __expf(acc[i][j][r] * iscale) : 0.0f;
          rs += e;
          sP[rowl * 136 + coll] = (bf16_t)e;
        }
        rs += __shfl_xor(rs, 1, 64);
        rs += __shfl_xor(rs, 2, 64);
        rs += __shfl_xor(rs, 4, 64);
        rs += __shfl_xor(rs, 8, 64);
        if (fr == 0) sL[w & 1][rowl] = rs;
      }
    }
    __syncthreads();

    #pragma unroll
    for (int i = 0; i < 2; ++i)
      #pragma unroll
      for (int r = 0; r < 4; ++r) {
        const int rowl = wm + i * 16 + kc * 4 + r;
        lsum[i][r] += sL[0][rowl] + sL[1][rowl];
      }
    #pragma unroll
    for (int s = 0; s < 8; ++s) {
      const int chunk = (w * 8 + s) * 64 + l;
      const int r = chunk >> 4;
      const int c = (chunk & 15) ^ (r & 7);
      async16(Vp + (long long)r * 2048 + t0 + c * 8, &sKV[(w * 8 + s) * 512]);
    }
    __builtin_amdgcn_s_waitcnt(0);
    __syncthreads();

    #pragma unroll
    for (int ks = 0; ks < 4; ++ks) {
      bf16x8 ap[2], bv[4];
      #pragma unroll
      for (int i = 0; i < 2; ++i)
        ap[i] = *(const bf16x8*)&sP[(wm + i * 16 + fr) * 136 + ks * 32 + kc * 8];
      #pragma unroll
      for (int j = 0; j < 4; ++j) {
        const int r = wn + j * 16 + fr;
        const int c = (ks * 4 + kc) ^ (r & 7);
        bv[j] = *(const bf16x8*)&sKV[r * 128 + c * 8];
      }
      #pragma unroll
      for (int i = 0; i < 2; ++i)
        #pragma unroll
        for (int j = 0; j < 4; ++j)
          oacc[i][j] = __builtin_amdgcn_mfma_f32_16x16x32_bf16(ap[i], bv[j], oacc[i][j], 0, 0, 0);
    }
    __syncthreads();
  }

  #pragma unroll
  for (int i = 0; i < 2; ++i) {
    #pragma unroll
    for (int r = 0; r < 4; ++r) {
      const int rowl = wm + i * 16 + kc * 4 + r;
      const float inv = 1.0f / lsum[i][r];
      #pragma unroll
      for (int j = 0; j < 4; ++j) {
        const int coll = wn + j * 16 + fr;
        ctx[(long long)(r0g + rowl) * 2048 + h * 128 + coll] = (bf16_t)(oacc[i][j][r] * inv);
      }
    }
  }
}

// dual f32 -> bf16 cast
__global__ __launch_bounds__(256)
void cvt2_f2b(const float* __restrict__ a, bf16_t* __restrict__ oa,
              const float* __restrict__ b, bf16_t* __restrict__ ob, int n)
{
  const float* in = blockIdx.y ? b : a;
  bf16_t* out = blockIdx.y ? ob : oa;
  const int i = (blockIdx.x * 256 + threadIdx.x) * 4;
  if (i >= n) return;
  const f32x4 v = *(const f32x4*)(in + i);
  bf16x4 o;
  #pragma unroll
  for (int j = 0; j < 4; ++j) o[j] = (bf16_t)v[j];
  *(bf16x4*)(out + i) = o;
}

// merged 128x2048 batch transposes: z<48 -> qkv_w, z>=48 -> dense_w
// out[z][c][r] = (bf16) in[z][r*2048 + c]
__global__ __launch_bounds__(256)
void transpose_k2(const float* __restrict__ in1, const float* __restrict__ in2,
                  bf16_t* __restrict__ o1, bf16_t* __restrict__ o2)
{
  __shared__ bf16_t sm[32][33];
  const int z  = blockIdx.z;
  const float* ip = (z < 48) ? in1 + (long long)z * 262144
                             : in2 + (long long)(z - 48) * 262144;
  bf16_t* op = (z < 48) ? o1 + (long long)z * 262144
                        : o2 + (long long)(z - 48) * 262144;
  const int r0 = blockIdx.x << 5;
  const int c0 = blockIdx.y << 5;
  const int tx = threadIdx.x & 31;
  const int ty = threadIdx.x >> 5;
  #pragma unroll
  for (int yy = ty; yy < 32; yy += 8)
    sm[yy][tx] = (bf16_t)ip[(long long)(r0 + yy) * 2048 + c0 + tx];
  __syncthreads();
  #pragma unroll
  for (int yy = ty; yy < 32; yy += 8)
    op[(long long)(c0 + yy) * 128 + r0 + tx] = sm[tx][yy];
}

// merged 128x128 per-head transposes of svd_qk and svd_vl (z = 0..31)
__global__ __launch_bounds__(256)
void transpose_rot(const float* __restrict__ qk, const float* __restrict__ vl,
                   bf16_t* __restrict__ oqk, bf16_t* __restrict__ ovl)
{
  __shared__ bf16_t sm[32][33];
  const int z  = blockIdx.z;
  const float* ip = (z < 16 ? qk : vl) + (long long)(z & 15) * 16384;
  bf16_t* op = (z < 16 ? oqk : ovl) + (long long)(z & 15) * 16384;
  const int r0 = blockIdx.x << 5;
  const int c0 = blockIdx.y << 5;
  const int tx = threadIdx.x & 31;
  const int ty = threadIdx.x >> 5;
  #pragma unroll
  for (int yy = ty; yy < 32; yy += 8)
    sm[yy][tx] = (bf16_t)ip[(long long)(r0 + yy) * 128 + c0 + tx];
  __syncthreads();
  #pragma unroll
  for (int yy = ty; yy < 32; yy += 8)
    op[(long long)(c0 + yy) * 128 + r0 + tx] = sm[tx][yy];
}

// brot[384h+128p+e] = sum_d qkv_b[384h+128p+d] * R[h,d,e]
__global__ void brot_k(const float* __restrict__ qkv_b,
                       const float* __restrict__ svd_qk,
                       const float* __restrict__ svd_vl,
                       bf16_t* __restrict__ brot)
{
  const int hp = blockIdx.x;
  const int h = hp / 3, p = hp % 3;
  const int e = threadIdx.x;
  const float* R = (p == 2 ? svd_vl : svd_qk) + h * 16384;
  const float* b = qkv_b + h * 384 + p * 128;
  float acc = 0.f;
  for (int d = 0; d < 128; ++d)
    acc += b[d] * R[d * 128 + e];
  brot[h * 384 + p * 128 + e] = (bf16_t)acc;
}

extern "C" void kernel_launch(void* const* d_in, const int* in_sizes, int n_in,
                              void* d_out, int out_size, void* d_ws, size_t ws_size,
                              hipStream_t stream)
{
  const float* hs      = (const float*)d_in[0];
  const float* qkv_w   = (const float*)d_in[2];
  const float* qkv_b   = (const float*)d_in[3];
  const float* svd_tok = (const float*)d_in[4];
  const float* svd_qk  = (const float*)d_in[5];
  const float* svd_vl  = (const float*)d_in[6];
  const float* dense_w = (const float*)d_in[7];
  const float* dense_b = (const float*)d_in[8];
  float* out = (float*)d_out;
  bf16_t* ws = (bf16_t*)d_ws;

  bf16_t* hsb    = ws;                    //  4,194,304
  bf16_t* stb    = ws +  4194304LL;       //  4,194,304
  bf16_t* Mbuf   = ws +  8388608LL;       //  4,194,304
  bf16_t* x2     = ws + 12582912LL;       //  4,194,304
  bf16_t* qkv_wT = ws + 16777216LL;       // 12,582,912
  bf16_t* Wrot   = ws + 29360128LL;       // 12,582,912
  bf16_t* mixed  = ws + 41943040LL;       // 12,582,912
  bf16_t* vT     = ws + 54525952LL;       //  4,194,304
  bf16_t* ctx    = ws + 58720256LL;       //  4,194,304
  bf16_t* dwT    = ws + 62914560LL;       //  4,194,304
  bf16_t* tsrT   = ws + 67108864LL;       //  4,194,304
  bf16_t* qkT    = ws + 71303168LL;       //    262,144
  bf16_t* vlT    = ws + 71565312LL;       //    262,144
  bf16_t* brot   = ws + 71827456LL;       //      6,144
  if (ws_size < 71833600ULL * 2ULL) return;

  const float iscale = 0.08838834764831845f;   // 1/sqrt(128)

  cvt2_f2b<<<dim3(4096, 2), 256, 0, stream>>>(hs, hsb, svd_tok, stb, 4194304);
  transpose_rot<<<dim3(4, 4, 32), 256, 0, stream>>>(svd_qk, svd_vl, qkT, vlT);
  transpose_k2<<<dim3(4, 64, 64), 256, 0, stream>>>(qkv_w, dense_w, qkv_wT, dwT);
  brot_k<<<dim3(48), 128, 0, stream>>>(qkv_b, svd_qk, svd_vl, brot);

  // M = svd_tok @ svd_tok^T
  gemm_nt64<<<dim3(16, 32), 256, 0, stream>>>(stb, stb, Mbuf, nullptr,
      2048, 2048, 2048, 2048, 1.0f, 0, nullptr);
  // x2 = hs @ M  (M symmetric -> NT ok)
  gemm_nt64<<<dim3(16, 32), 256, 0, stream>>>(hsb, Mbuf, x2, nullptr,
      2048, 2048, 2048, 2048, 1.0f, 0, nullptr);
  // Wrot (48 batches) + tsrT (16 batches) in one launch
  gemm_prep<<<dim3(16, 1, 64), 256, 0, stream>>>(qkT, vlT, qkv_wT, dwT, Wrot, tsrT);
  // mixed = x2 @ Wrot^T + brot   (v-tiles mirrored into vT)
  gemm_nt64<<<dim3(48, 32), 256, 0, stream>>>(x2, Wrot, mixed, brot,
      2048, 2048, 2048, 6144, 1.0f, 8 | 16, vT);
  // fused attention -> ctx
  flash_k<<<dim3(32, 16), 256, 0, stream>>>(mixed, vT, ctx, iscale);
  // out = ctx @ tsrT^T + dense_b  (f32 store)
  gemm_nt64<<<dim3(16, 32), 256, 0, stream>>>(ctx, tsrT, out, dense_b,
      2048, 2048, 2048, 2048, 1.0f, 4, nullptr);
}

// Round 7
// 438.117 us; speedup vs baseline: 1.0811x; 1.0811x over previous
//
#include <hip/hip_runtime.h>
#include <hip/hip_bf16.h>
#include <stdint.h>
#include <math.h>

// ---------------------------------------------------------------------------
// Attention_74852690035363 — f32 I/O, bf16 MFMA compute.
//   M     = svd_tok·svd_tokᵀ            [nt64 BK=64, 512 blk]
//   x2    = hs·M (M symmetric)          [nt64 BK=64]
//   prep  = Wrot (48 batches) + tsrT (16 batches) in one launch [BK=64]
//   mixed = x2·Wrotᵀ + brot             [128² tile BK=64, 768 blk = 3/CU]
//   vT    = transpose of V blocks of mixed (coalesced kernel)
//   flash = fused exp(scale·q·kᵀ) causal / rowsum / P·V -> ctx
//   out   = ctx·tsrTᵀ + dense_b         [nt64 BK=64, f32 store]
// LDS tiles 16B-chunk XOR-swizzled (verified: SQ_LDS_BANK_CONFLICT = 0).
// BK=64: two 32-k halves per barrier -> half the vmcnt(0)+barrier drains.
// ---------------------------------------------------------------------------

typedef __bf16 bf16_t;
typedef __bf16 bf16x8 __attribute__((ext_vector_type(8)));
typedef __bf16 bf16x4 __attribute__((ext_vector_type(4)));
typedef float  f32x4  __attribute__((ext_vector_type(4)));

__device__ __forceinline__ void async16(const void* g, void* l) {
  __builtin_amdgcn_global_load_lds(
      (const __attribute__((address_space(1))) void*)(uintptr_t)g,
      (__attribute__((address_space(3))) void*)(uint32_t)(uintptr_t)l,
      16, 0, 0);
}

// ---------------- 128x128-tile NT GEMM, BK=64 ------------------------------
// flags&4: f32 C + f32 bias ; flags&8: bf16 bias
__global__ __launch_bounds__(256)
void gemm_nt128(const bf16_t* __restrict__ A, const bf16_t* __restrict__ B,
                void* __restrict__ Cv, const void* __restrict__ biasv,
                int K, int lda, int ldb, int ldc, float alpha, int flags)
{
  const int bm0 = blockIdx.y * 128;
  const int bn0 = blockIdx.x * 128;

  __shared__ bf16_t shA[8192];   // 2 halves x 128x32
  __shared__ bf16_t shB[8192];

  const int t  = threadIdx.x;
  const int w  = t >> 6;
  const int l  = t & 63;
  const int wm = (w >> 1) * 64;
  const int wn = (w & 1) * 64;
  const int r0 = l >> 2;
  const int c0 = ((l & 3) ^ ((l >> 3) & 3)) * 8;
  const int fr = l & 15;
  const int kc = l >> 4;
  const int swr = ((fr >> 1) & 3);

  f32x4 acc[4][4];
  #pragma unroll
  for (int i = 0; i < 4; ++i)
    #pragma unroll
    for (int j = 0; j < 4; ++j)
      #pragma unroll
      for (int r = 0; r < 4; ++r)
        acc[i][j][r] = 0.0f;

  for (int k0 = 0; k0 < K; k0 += 64) {
    #pragma unroll
    for (int u = 0; u < 4; ++u) {
      const int seg  = u * 4 + w;          // 0..15
      const int half = seg >> 3;
      const int s8   = seg & 7;
      const int row  = s8 * 16 + r0;
      const int gk   = k0 + half * 32 + c0;
      async16(A + (long long)(bm0 + row) * lda + gk, &shA[half * 4096 + s8 * 512]);
      async16(B + (long long)(bn0 + row) * ldb + gk, &shB[half * 4096 + s8 * 512]);
    }
    __builtin_amdgcn_s_waitcnt(0);
    __syncthreads();

    const int rc = (kc ^ swr) * 8;
    #pragma unroll
    for (int h = 0; h < 2; ++h) {
      bf16x8 af[4], bfv[4];
      #pragma unroll
      for (int i = 0; i < 4; ++i) {
        af[i]  = *(const bf16x8*)&shA[h * 4096 + (wm + i * 16 + fr) * 32 + rc];
        bfv[i] = *(const bf16x8*)&shB[h * 4096 + (wn + i * 16 + fr) * 32 + rc];
      }
      #pragma unroll
      for (int i = 0; i < 4; ++i)
        #pragma unroll
        for (int j = 0; j < 4; ++j)
          acc[i][j] = __builtin_amdgcn_mfma_f32_16x16x32_bf16(af[i], bfv[j], acc[i][j], 0, 0, 0);
    }
    __syncthreads();
  }

  const int cc = l & 15;
  const int rq = (l >> 4) * 4;
  if (flags & 4) {
    float* C = (float*)Cv;
    const float* bias = (const float*)biasv;
    #pragma unroll
    for (int j = 0; j < 4; ++j) {
      const int col = bn0 + wn + j * 16 + cc;
      const float bv = bias ? bias[col] : 0.0f;
      #pragma unroll
      for (int i = 0; i < 4; ++i)
        #pragma unroll
        for (int r = 0; r < 4; ++r) {
          const int row = bm0 + wm + i * 16 + rq + r;
          C[(long long)row * ldc + col] = acc[i][j][r] * alpha + bv;
        }
    }
  } else {
    bf16_t* C = (bf16_t*)Cv;
    const bf16_t* bias = (flags & 8) ? (const bf16_t*)biasv : nullptr;
    #pragma unroll
    for (int j = 0; j < 4; ++j) {
      const int col = bn0 + wn + j * 16 + cc;
      const float bv = bias ? (float)bias[col] : 0.0f;
      #pragma unroll
      for (int i = 0; i < 4; ++i)
        #pragma unroll
        for (int r = 0; r < 4; ++r) {
          const int row = bm0 + wm + i * 16 + rq + r;
          C[(long long)row * ldc + col] = (bf16_t)(acc[i][j][r] * alpha + bv);
        }
    }
  }
}

// ---------------- 64x128-tile NT GEMM, BK=64 -------------------------------
// flags&4: f32 C + f32 bias
__global__ __launch_bounds__(256)
void gemm_nt64(const bf16_t* __restrict__ A, const bf16_t* __restrict__ B,
               void* __restrict__ Cv, const void* __restrict__ biasv,
               int K, int lda, int ldb, int ldc, float alpha, int flags)
{
  const int bm0 = blockIdx.y * 64;
  const int bn0 = blockIdx.x * 128;

  __shared__ bf16_t shA[4096];   // 2 halves x 64x32
  __shared__ bf16_t shB[8192];   // 2 halves x 128x32

  const int t  = threadIdx.x;
  const int w  = t >> 6;
  const int l  = t & 63;
  const int wm = (w >> 1) * 32;
  const int wn = (w & 1) * 64;
  const int r0 = l >> 2;
  const int c0 = ((l & 3) ^ ((l >> 3) & 3)) * 8;
  const int fr = l & 15;
  const int kc = l >> 4;
  const int swr = ((fr >> 1) & 3);

  f32x4 acc[2][4];
  #pragma unroll
  for (int i = 0; i < 2; ++i)
    #pragma unroll
    for (int j = 0; j < 4; ++j)
      #pragma unroll
      for (int r = 0; r < 4; ++r)
        acc[i][j][r] = 0.0f;

  for (int k0 = 0; k0 < K; k0 += 64) {
    #pragma unroll
    for (int u = 0; u < 2; ++u) {          // A: 8 segments (2 halves x 4)
      const int seg  = u * 4 + w;
      const int half = seg >> 2;
      const int s4   = seg & 3;
      const int row  = s4 * 16 + r0;
      async16(A + (long long)(bm0 + row) * lda + (k0 + half * 32 + c0),
              &shA[half * 2048 + s4 * 512]);
    }
    #pragma unroll
    for (int u = 0; u < 4; ++u) {          // B: 16 segments (2 halves x 8)
      const int seg  = u * 4 + w;
      const int half = seg >> 3;
      const int s8   = seg & 7;
      const int row  = s8 * 16 + r0;
      async16(B + (long long)(bn0 + row) * ldb + (k0 + half * 32 + c0),
              &shB[half * 4096 + s8 * 512]);
    }
    __builtin_amdgcn_s_waitcnt(0);
    __syncthreads();

    const int rc = (kc ^ swr) * 8;
    #pragma unroll
    for (int h = 0; h < 2; ++h) {
      bf16x8 af[2], bfv[4];
      #pragma unroll
      for (int i = 0; i < 2; ++i)
        af[i]  = *(const bf16x8*)&shA[h * 2048 + (wm + i * 16 + fr) * 32 + rc];
      #pragma unroll
      for (int j = 0; j < 4; ++j)
        bfv[j] = *(const bf16x8*)&shB[h * 4096 + (wn + j * 16 + fr) * 32 + rc];
      #pragma unroll
      for (int i = 0; i < 2; ++i)
        #pragma unroll
        for (int j = 0; j < 4; ++j)
          acc[i][j] = __builtin_amdgcn_mfma_f32_16x16x32_bf16(af[i], bfv[j], acc[i][j], 0, 0, 0);
    }
    __syncthreads();
  }

  const int cc = l & 15;
  const int rq = (l >> 4) * 4;
  if (flags & 4) {
    float* C = (float*)Cv;
    const float* bias = (const float*)biasv;
    #pragma unroll
    for (int j = 0; j < 4; ++j) {
      const int col = bn0 + wn + j * 16 + cc;
      const float bv = bias ? bias[col] : 0.0f;
      #pragma unroll
      for (int i = 0; i < 2; ++i)
        #pragma unroll
        for (int r = 0; r < 4; ++r) {
          const int row = bm0 + wm + i * 16 + rq + r;
          C[(long long)row * ldc + col] = acc[i][j][r] * alpha + bv;
        }
    }
  } else {
    bf16_t* C = (bf16_t*)Cv;
    #pragma unroll
    for (int j = 0; j < 4; ++j) {
      const int col = bn0 + wn + j * 16 + cc;
      #pragma unroll
      for (int i = 0; i < 2; ++i)
        #pragma unroll
        for (int r = 0; r < 4; ++r) {
          const int row = bm0 + wm + i * 16 + rq + r;
          C[(long long)row * ldc + col] = (bf16_t)(acc[i][j][r] * alpha);
        }
    }
  }
}

// ---------------- merged prep GEMMs: Wrot (z<48) + tsrT (z>=48), BK=64 -----
__global__ __launch_bounds__(256)
void gemm_prep(const bf16_t* __restrict__ qkT, const bf16_t* __restrict__ vlT,
               const bf16_t* __restrict__ qkv_wT, const bf16_t* __restrict__ dwT,
               bf16_t* __restrict__ Wrot, bf16_t* __restrict__ tsrT)
{
  const int z = blockIdx.z;
  const bf16_t* A;
  const bf16_t* B;
  bf16_t* C;
  int bm0, bn0;
  if (z < 48) {
    const int h = z / 3, p = z - 3 * h;
    A = (p == 2 ? vlT : qkT) + h * 16384;
    B = qkv_wT + (long long)z * 262144;
    C = Wrot + (long long)z * 262144;
    bm0 = 0;
    bn0 = blockIdx.x * 128;
  } else {
    const int b = z - 48;
    A = dwT + (long long)b * 262144;
    B = vlT + b * 16384;
    C = tsrT;
    bm0 = blockIdx.x * 128;
    bn0 = b * 128;
  }

  __shared__ bf16_t shA[8192];
  __shared__ bf16_t shB[8192];

  const int t  = threadIdx.x;
  const int w  = t >> 6;
  const int l  = t & 63;
  const int wm = (w >> 1) * 64;
  const int wn = (w & 1) * 64;
  const int r0 = l >> 2;
  const int c0 = ((l & 3) ^ ((l >> 3) & 3)) * 8;
  const int fr = l & 15;
  const int kc = l >> 4;
  const int swr = ((fr >> 1) & 3);
  const int arow0 = (z < 48 ? 0 : bm0);
  const int brow0 = (z < 48 ? bn0 : 0);

  f32x4 acc[4][4];
  #pragma unroll
  for (int i = 0; i < 4; ++i)
    #pragma unroll
    for (int j = 0; j < 4; ++j)
      #pragma unroll
      for (int r = 0; r < 4; ++r)
        acc[i][j][r] = 0.0f;

  for (int k0 = 0; k0 < 128; k0 += 64) {
    #pragma unroll
    for (int u = 0; u < 4; ++u) {
      const int seg  = u * 4 + w;
      const int half = seg >> 3;
      const int s8   = seg & 7;
      const int row  = s8 * 16 + r0;
      const int gk   = k0 + half * 32 + c0;
      async16(A + (long long)(arow0 + row) * 128 + gk, &shA[half * 4096 + s8 * 512]);
      async16(B + (long long)(brow0 + row) * 128 + gk, &shB[half * 4096 + s8 * 512]);
    }
    __builtin_amdgcn_s_waitcnt(0);
    __syncthreads();

    const int rc = (kc ^ swr) * 8;
    #pragma unroll
    for (int h = 0; h < 2; ++h) {
      bf16x8 af[4], bfv[4];
      #pragma unroll
      for (int i = 0; i < 4; ++i) {
        af[i]  = *(const bf16x8*)&shA[h * 4096 + (wm + i * 16 + fr) * 32 + rc];
        bfv[i] = *(const bf16x8*)&shB[h * 4096 + (wn + i * 16 + fr) * 32 + rc];
      }
      #pragma unroll
      for (int i = 0; i < 4; ++i)
        #pragma unroll
        for (int j = 0; j < 4; ++j)
          acc[i][j] = __builtin_amdgcn_mfma_f32_16x16x32_bf16(af[i], bfv[j], acc[i][j], 0, 0, 0);
    }
    __syncthreads();
  }

  const int cc = l & 15;
  const int rq = (l >> 4) * 4;
  #pragma unroll
  for (int j = 0; j < 4; ++j) {
    const int col = bn0 + wn + j * 16 + cc;
    #pragma unroll
    for (int i = 0; i < 4; ++i)
      #pragma unroll
      for (int r = 0; r < 4; ++r) {
        const int row = arow0 + wm + i * 16 + rq + r;
        C[(long long)row * 2048 + col] = (bf16_t)acc[i][j][r];
      }
  }
}

// ---------------------------------------------------------------------------
// Flash attention (verified rounds 4-6): one block = 64 q-rows x one head.
// ---------------------------------------------------------------------------
__global__ __launch_bounds__(256)
void flash_k(const bf16_t* __restrict__ mixed, const bf16_t* __restrict__ vT,
             bf16_t* __restrict__ ctx, float iscale)
{
  const int h  = blockIdx.y;
  const int qt = 31 - (int)blockIdx.x;
  const int r0g = qt * 64;
  const int niter = (qt >> 1) + 1;
  const bf16_t* Qp = mixed + h * 384;
  const bf16_t* Kp = mixed + h * 384 + 128;
  const bf16_t* Vp = vT + (long long)h * 262144;

  __shared__ bf16_t sKV[128 * 128];
  __shared__ bf16_t sP[64 * 136];
  __shared__ float  sL[2][64];

  const int t  = threadIdx.x;
  const int w  = t >> 6;
  const int l  = t & 63;
  const int wm = (w >> 1) * 32;
  const int wn = (w & 1) * 64;
  const int fr = l & 15;
  const int kc = l >> 4;

  bf16x8 aq[2][4];
  #pragma unroll
  for (int i = 0; i < 2; ++i)
    #pragma unroll
    for (int ks = 0; ks < 4; ++ks)
      aq[i][ks] = *(const bf16x8*)(Qp + (long long)(r0g + wm + i * 16 + fr) * 6144
                                      + ks * 32 + kc * 8);

  f32x4 oacc[2][4];
  #pragma unroll
  for (int i = 0; i < 2; ++i)
    #pragma unroll
    for (int j = 0; j < 4; ++j)
      #pragma unroll
      for (int r = 0; r < 4; ++r) oacc[i][j][r] = 0.0f;
  float lsum[2][4];
  #pragma unroll
  for (int i = 0; i < 2; ++i)
    #pragma unroll
    for (int r = 0; r < 4; ++r) lsum[i][r] = 0.0f;

  for (int it = 0; it < niter; ++it) {
    const int t0 = it * 128;
    #pragma unroll
    for (int s = 0; s < 8; ++s) {
      const int chunk = (w * 8 + s) * 64 + l;
      const int r = chunk >> 4;
      const int c = (chunk & 15) ^ (r & 7);
      async16(Kp + (long long)(t0 + r) * 6144 + c * 8, &sKV[(w * 8 + s) * 512]);
    }
    __builtin_amdgcn_s_waitcnt(0);
    __syncthreads();

    f32x4 acc[2][4];
    #pragma unroll
    for (int i = 0; i < 2; ++i)
      #pragma unroll
      for (int j = 0; j < 4; ++j)
        #pragma unroll
        for (int r = 0; r < 4; ++r) acc[i][j][r] = 0.0f;
    #pragma unroll
    for (int ks = 0; ks < 4; ++ks) {
      bf16x8 bk[4];
      #pragma unroll
      for (int j = 0; j < 4; ++j) {
        const int r = wn + j * 16 + fr;
        const int c = (ks * 4 + kc) ^ (r & 7);
        bk[j] = *(const bf16x8*)&sKV[r * 128 + c * 8];
      }
      #pragma unroll
      for (int i = 0; i < 2; ++i)
        #pragma unroll
        for (int j = 0; j < 4; ++j)
          acc[i][j] = __builtin_amdgcn_mfma_f32_16x16x32_bf16(aq[i][ks], bk[j], acc[i][j], 0, 0, 0);
    }

    #pragma unroll
    for (int i = 0; i < 2; ++i) {
      #pragma unroll
      for (int r = 0; r < 4; ++r) {
        const int rowl = wm + i * 16 + kc * 4 + r;
        const int Rg = r0g + rowl;
        float rs = 0.f;
        #pragma unroll
        for (int j = 0; j < 4; ++j) {
          const int coll = wn + j * 16 + fr;
          const float e = (t0 + coll <= Rg) ? __expf(acc[i][j][r] * iscale) : 0.0f;
          rs += e;
          sP[rowl * 136 + coll] = (bf16_t)e;
        }
        rs += __shfl_xor(rs, 1, 64);
        rs += __shfl_xor(rs, 2, 64);
        rs += __shfl_xor(rs, 4, 64);
        rs += __shfl_xor(rs, 8, 64);
        if (fr == 0) sL[w & 1][rowl] = rs;
      }
    }
    __syncthreads();

    #pragma unroll
    for (int i = 0; i < 2; ++i)
      #pragma unroll
      for (int r = 0; r < 4; ++r) {
        const int rowl = wm + i * 16 + kc * 4 + r;
        lsum[i][r] += sL[0][rowl] + sL[1][rowl];
      }
    #pragma unroll
    for (int s = 0; s < 8; ++s) {
      const int chunk = (w * 8 + s) * 64 + l;
      const int r = chunk >> 4;
      const int c = (chunk & 15) ^ (r & 7);
      async16(Vp + (long long)r * 2048 + t0 + c * 8, &sKV[(w * 8 + s) * 512]);
    }
    __builtin_amdgcn_s_waitcnt(0);
    __syncthreads();

    #pragma unroll
    for (int ks = 0; ks < 4; ++ks) {
      bf16x8 ap[2], bv[4];
      #pragma unroll
      for (int i = 0; i < 2; ++i)
        ap[i] = *(const bf16x8*)&sP[(wm + i * 16 + fr) * 136 + ks * 32 + kc * 8];
      #pragma unroll
      for (int j = 0; j < 4; ++j) {
        const int r = wn + j * 16 + fr;
        const int c = (ks * 4 + kc) ^ (r & 7);
        bv[j] = *(const bf16x8*)&sKV[r * 128 + c * 8];
      }
      #pragma unroll
      for (int i = 0; i < 2; ++i)
        #pragma unroll
        for (int j = 0; j < 4; ++j)
          oacc[i][j] = __builtin_amdgcn_mfma_f32_16x16x32_bf16(ap[i], bv[j], oacc[i][j], 0, 0, 0);
    }
    __syncthreads();
  }

  #pragma unroll
  for (int i = 0; i < 2; ++i) {
    #pragma unroll
    for (int r = 0; r < 4; ++r) {
      const int rowl = wm + i * 16 + kc * 4 + r;
      const float inv = 1.0f / lsum[i][r];
      #pragma unroll
      for (int j = 0; j < 4; ++j) {
        const int coll = wn + j * 16 + fr;
        ctx[(long long)(r0g + rowl) * 2048 + h * 128 + coll] = (bf16_t)(oacc[i][j][r] * inv);
      }
    }
  }
}

// dual f32 -> bf16 cast
__global__ __launch_bounds__(256)
void cvt2_f2b(const float* __restrict__ a, bf16_t* __restrict__ oa,
              const float* __restrict__ b, bf16_t* __restrict__ ob, int n)
{
  const float* in = blockIdx.y ? b : a;
  bf16_t* out = blockIdx.y ? ob : oa;
  const int i = (blockIdx.x * 256 + threadIdx.x) * 4;
  if (i >= n) return;
  const f32x4 v = *(const f32x4*)(in + i);
  bf16x4 o;
  #pragma unroll
  for (int j = 0; j < 4; ++j) o[j] = (bf16_t)v[j];
  *(bf16x4*)(out + i) = o;
}

// merged 128x2048 batch transposes: z<48 -> qkv_w, z>=48 -> dense_w
__global__ __launch_bounds__(256)
void transpose_k2(const float* __restrict__ in1, const float* __restrict__ in2,
                  bf16_t* __restrict__ o1, bf16_t* __restrict__ o2)
{
  __shared__ bf16_t sm[32][33];
  const int z  = blockIdx.z;
  const float* ip = (z < 48) ? in1 + (long long)z * 262144
                             : in2 + (long long)(z - 48) * 262144;
  bf16_t* op = (z < 48) ? o1 + (long long)z * 262144
                        : o2 + (long long)(z - 48) * 262144;
  const int r0 = blockIdx.x << 5;
  const int c0 = blockIdx.y << 5;
  const int tx = threadIdx.x & 31;
  const int ty = threadIdx.x >> 5;
  #pragma unroll
  for (int yy = ty; yy < 32; yy += 8)
    sm[yy][tx] = (bf16_t)ip[(long long)(r0 + yy) * 2048 + c0 + tx];
  __syncthreads();
  #pragma unroll
  for (int yy = ty; yy < 32; yy += 8)
    op[(long long)(c0 + yy) * 128 + r0 + tx] = sm[tx][yy];
}

// merged 128x128 per-head transposes of svd_qk and svd_vl (z = 0..31)
__global__ __launch_bounds__(256)
void transpose_rot(const float* __restrict__ qk, const float* __restrict__ vl,
                   bf16_t* __restrict__ oqk, bf16_t* __restrict__ ovl)
{
  __shared__ bf16_t sm[32][33];
  const int z  = blockIdx.z;
  const float* ip = (z < 16 ? qk : vl) + (long long)(z & 15) * 16384;
  bf16_t* op = (z < 16 ? oqk : ovl) + (long long)(z & 15) * 16384;
  const int r0 = blockIdx.x << 5;
  const int c0 = blockIdx.y << 5;
  const int tx = threadIdx.x & 31;
  const int ty = threadIdx.x >> 5;
  #pragma unroll
  for (int yy = ty; yy < 32; yy += 8)
    sm[yy][tx] = (bf16_t)ip[(long long)(r0 + yy) * 128 + c0 + tx];
  __syncthreads();
  #pragma unroll
  for (int yy = ty; yy < 32; yy += 8)
    op[(long long)(c0 + yy) * 128 + r0 + tx] = sm[tx][yy];
}

// bf16 -> bf16 transpose (coalesced both sides via LDS tile)
__global__ __launch_bounds__(256)
void transpose_b2b(const bf16_t* __restrict__ in, bf16_t* __restrict__ out,
                   int R, long long zsi, int rsi, long long zso)
{
  __shared__ bf16_t sm[32][33];
  const int z  = blockIdx.z;
  const int r0 = blockIdx.x << 5;
  const int c0 = blockIdx.y << 5;
  const int tx = threadIdx.x & 31;
  const int ty = threadIdx.x >> 5;
  const bf16_t* ip = in + (long long)z * zsi;
  bf16_t* op = out + (long long)z * zso;
  #pragma unroll
  for (int yy = ty; yy < 32; yy += 8)
    sm[yy][tx] = ip[(long long)(r0 + yy) * rsi + c0 + tx];
  __syncthreads();
  #pragma unroll
  for (int yy = ty; yy < 32; yy += 8)
    op[(long long)(c0 + yy) * R + r0 + tx] = sm[tx][yy];
}

// brot[384h+128p+e] = sum_d qkv_b[384h+128p+d] * R[h,d,e]
__global__ void brot_k(const float* __restrict__ qkv_b,
                       const float* __restrict__ svd_qk,
                       const float* __restrict__ svd_vl,
                       bf16_t* __restrict__ brot)
{
  const int hp = blockIdx.x;
  const int h = hp / 3, p = hp % 3;
  const int e = threadIdx.x;
  const float* R = (p == 2 ? svd_vl : svd_qk) + h * 16384;
  const float* b = qkv_b + h * 384 + p * 128;
  float acc = 0.f;
  for (int d = 0; d < 128; ++d)
    acc += b[d] * R[d * 128 + e];
  brot[h * 384 + p * 128 + e] = (bf16_t)acc;
}

extern "C" void kernel_launch(void* const* d_in, const int* in_sizes, int n_in,
                              void* d_out, int out_size, void* d_ws, size_t ws_size,
                              hipStream_t stream)
{
  const float* hs      = (const float*)d_in[0];
  const float* qkv_w   = (const float*)d_in[2];
  const float* qkv_b   = (const float*)d_in[3];
  const float* svd_tok = (const float*)d_in[4];
  const float* svd_qk  = (const float*)d_in[5];
  const float* svd_vl  = (const float*)d_in[6];
  const float* dense_w = (const float*)d_in[7];
  const float* dense_b = (const float*)d_in[8];
  float* out = (float*)d_out;
  bf16_t* ws = (bf16_t*)d_ws;

  bf16_t* hsb    = ws;                    //  4,194,304
  bf16_t* stb    = ws +  4194304LL;       //  4,194,304
  bf16_t* Mbuf   = ws +  8388608LL;       //  4,194,304
  bf16_t* x2     = ws + 12582912LL;       //  4,194,304
  bf16_t* qkv_wT = ws + 16777216LL;       // 12,582,912
  bf16_t* Wrot   = ws + 29360128LL;       // 12,582,912
  bf16_t* mixed  = ws + 41943040LL;       // 12,582,912
  bf16_t* vT     = ws + 54525952LL;       //  4,194,304
  bf16_t* ctx    = ws + 58720256LL;       //  4,194,304
  bf16_t* dwT    = ws + 62914560LL;       //  4,194,304
  bf16_t* tsrT   = ws + 67108864LL;       //  4,194,304
  bf16_t* qkT    = ws + 71303168LL;       //    262,144
  bf16_t* vlT    = ws + 71565312LL;       //    262,144
  bf16_t* brot   = ws + 71827456LL;       //      6,144
  if (ws_size < 71833600ULL * 2ULL) return;

  const float iscale = 0.08838834764831845f;   // 1/sqrt(128)

  cvt2_f2b<<<dim3(4096, 2), 256, 0, stream>>>(hs, hsb, svd_tok, stb, 4194304);
  transpose_rot<<<dim3(4, 4, 32), 256, 0, stream>>>(svd_qk, svd_vl, qkT, vlT);
  transpose_k2<<<dim3(4, 64, 64), 256, 0, stream>>>(qkv_w, dense_w, qkv_wT, dwT);
  brot_k<<<dim3(48), 128, 0, stream>>>(qkv_b, svd_qk, svd_vl, brot);

  // M = svd_tok @ svd_tok^T
  gemm_nt64<<<dim3(16, 32), 256, 0, stream>>>(stb, stb, Mbuf, nullptr,
      2048, 2048, 2048, 2048, 1.0f, 0);
  // x2 = hs @ M  (M symmetric -> NT ok)
  gemm_nt64<<<dim3(16, 32), 256, 0, stream>>>(hsb, Mbuf, x2, nullptr,
      2048, 2048, 2048, 2048, 1.0f, 0);
  // Wrot (48 batches) + tsrT (16 batches) in one launch
  gemm_prep<<<dim3(16, 1, 64), 256, 0, stream>>>(qkT, vlT, qkv_wT, dwT, Wrot, tsrT);
  // mixed = x2 @ Wrot^T + brot  (128^2 tile, BK=64)
  gemm_nt128<<<dim3(48, 16), 256, 0, stream>>>(x2, Wrot, mixed, brot,
      2048, 2048, 2048, 6144, 1.0f, 8);
  // vT[h][e][t] = mixed[t][384h+256+e]
  transpose_b2b<<<dim3(64, 4, 16), 256, 0, stream>>>(mixed + 256, vT, 2048, 384, 6144, 262144);
  // fused attention -> ctx
  flash_k<<<dim3(32, 16), 256, 0, stream>>>(mixed, vT, ctx, iscale);
  // out = ctx @ tsrT^T + dense_b  (f32 store)
  gemm_nt64<<<dim3(16, 32), 256, 0, stream>>>(ctx, tsrT, out, dense_b,
      2048, 2048, 2048, 2048, 1.0f, 4);
}